// Round 10
// baseline (3287.701 us; speedup 1.0000x reference)
//
#include <hip/hip_runtime.h>
#include <math.h>
#include <stdint.h>

#define EPSv 1e-5f

typedef short short8 __attribute__((ext_vector_type(8)));
typedef float floatx4 __attribute__((ext_vector_type(4)));

__device__ __forceinline__ unsigned short f2bf(float x) {
  unsigned u = __float_as_uint(x);
  unsigned r = (u + 0x7fffu + ((u >> 16) & 1u)) >> 16;
  return (unsigned short)r;
}

// global->LDS direct DMA, 16B/lane (explicit address spaces; CK cast pattern).
__device__ __forceinline__ void gld_lds16(const void* g, void* l) {
  __builtin_amdgcn_global_load_lds(
      (const __attribute__((address_space(1))) unsigned*)(uintptr_t)g,
      (__attribute__((address_space(3))) unsigned*)(uintptr_t)l,
      16, 0, 0);
}

// last-block ticket: reduce statp (80 x 512 partials) -> dense statd (mu[256], rs[256]).
__device__ __forceinline__ void stat_finalize(const float* __restrict__ statp,
                                              float* __restrict__ statd,
                                              int* __restrict__ cnt, int expect, int t) {
  __threadfence();
  __shared__ int isLast;
  if (t == 0) isLast = (atomicAdd(cnt, 1) == expect - 1) ? 1 : 0;
  __syncthreads();
  if (isLast) {
    __threadfence();
    float s = 0.f, s2 = 0.f;
    for (int p = 0; p < 80; ++p) {
      s  += statp[(size_t)p*512 + t];
      s2 += statp[(size_t)p*512 + 256 + t];
    }
    float mu = s * (1.0f/9600.0f);
    float var = s2 * (1.0f/9600.0f) - mu*mu;
    statd[t] = mu;
    statd[256 + t] = rsqrtf(var + EPSv);
    __threadfence();
    if (t == 0) atomicExch(cnt, 0);
  }
}

__global__ void k_zeroi(int* __restrict__ p) { if (threadIdx.x == 0) p[0] = 0; }

// ---------------- gamma/beta via k-slice partials ----------------
__global__ __launch_bounds__(256) void k_gb_part(const float* __restrict__ spk,
                             const float* __restrict__ noise,
                             const float* __restrict__ g_w, const float* __restrict__ b_w,
                             const float* __restrict__ tl_g_w, const float* __restrict__ tl_b_w,
                             float* __restrict__ gpart, float* __restrict__ bpart) {
  __shared__ float condl[16][32];
  int i = blockIdx.x, ks = blockIdx.y;
  int t = threadIdx.x;
  for (int idx = t; idx < 512; idx += 256) {
    int b = idx >> 5, kk = idx & 31;
    int k = ks*32 + kk;
    condl[b][kk] = (k < 128) ? spk[b*128 + k] : noise[b*128 + k - 128];
  }
  __syncthreads();
  const float *gw, *bw;
  if (i < 30) { gw = g_w + (size_t)i*65536; bw = b_w + (size_t)i*65536; }
  else        { gw = tl_g_w + (size_t)(i-30)*65536; bw = tl_b_w + (size_t)(i-30)*65536; }
  int co = t;
  float g[16], bt[16];
  #pragma unroll
  for (int b = 0; b < 16; ++b) { g[b] = 0.f; bt[b] = 0.f; }
  for (int kk = 0; kk < 32; ++kk) {
    float gwv = gw[(size_t)(ks*32 + kk)*256 + co];
    float bwv = bw[(size_t)(ks*32 + kk)*256 + co];
    #pragma unroll
    for (int b = 0; b < 16; ++b) {
      float cv = condl[b][kk];
      g[b]  = fmaf(cv, gwv, g[b]);
      bt[b] = fmaf(cv, bwv, bt[b]);
    }
  }
  size_t base = ((size_t)(i*8 + ks)*16)*256 + co;
  #pragma unroll
  for (int b = 0; b < 16; ++b) {
    gpart[base + (size_t)b*256] = g[b];
    bpart[base + (size_t)b*256] = bt[b];
  }
}

__global__ void k_gb_red(const float* __restrict__ gpart, const float* __restrict__ bpart,
                         const float* __restrict__ g_b, const float* __restrict__ b_b,
                         const float* __restrict__ tl_g_b, const float* __restrict__ tl_b_b,
                         float* __restrict__ gammas, float* __restrict__ betas) {
  int idx = blockIdx.x*256 + threadIdx.x;    // 0..131071
  int i = idx >> 12, rem = idx & 4095;
  int co = rem & 255;
  float gs = 0.f, bs = 0.f;
  #pragma unroll
  for (int ks = 0; ks < 8; ++ks) {
    size_t p = ((size_t)(i*8 + ks) << 12) + rem;
    gs += gpart[p];
    bs += bpart[p];
  }
  float gbias = (i < 30) ? g_b[i*256 + co] : tl_g_b[(i-30)*256 + co];
  float bbias = (i < 30) ? b_b[i*256 + co] : tl_b_b[(i-30)*256 + co];
  gammas[idx] = 1.0f + gs + gbias;
  betas [idx] = bs + bbias;
}

// ---------------- weight prepack ----------------
template<int TAPS>
__device__ __forceinline__ void wprep_body(const float* __restrict__ src,
                                           unsigned short* __restrict__ dst,
                                           int cotile, int chunk, int t) {
  int cow = t >> 2, ci8 = (t & 3) * 8;
  const float* s0 = src + ((size_t)(cotile*64 + cow)*256 + chunk*32 + ci8)*TAPS;
  float v[8*TAPS];
  #pragma unroll
  for (int i = 0; i < 8*TAPS; ++i) v[i] = s0[i];
  unsigned short* dblk = dst + (size_t)cotile*(8*TAPS*4096) + (size_t)chunk*(TAPS*4096);
  #pragma unroll
  for (int tap = 0; tap < TAPS; ++tap) {
    unsigned hi2[4], lo2[4];
    #pragma unroll
    for (int jj = 0; jj < 4; ++jj) {
      float a = v[(jj*2+0)*TAPS + tap], b = v[(jj*2+1)*TAPS + tap];
      unsigned short ha = f2bf(a), hb = f2bf(b);
      unsigned short la = f2bf(a - __uint_as_float((unsigned)ha << 16));
      unsigned short lb = f2bf(b - __uint_as_float((unsigned)hb << 16));
      hi2[jj] = (unsigned)ha | ((unsigned)hb << 16);
      lo2[jj] = (unsigned)la | ((unsigned)lb << 16);
    }
    uint4 H; H.x = hi2[0]; H.y = hi2[1]; H.z = hi2[2]; H.w = hi2[3];
    uint4 L; L.x = lo2[0]; L.y = lo2[1]; L.z = lo2[2]; L.w = lo2[3];
    *(uint4*)(dblk + (size_t)(tap*2)*2048 + cow*32 + ci8) = H;
    *(uint4*)(dblk + (size_t)(tap*2+1)*2048 + cow*32 + ci8) = L;
  }
}

__global__ __launch_bounds__(256) void k_wprep(const float* __restrict__ conv_w,
                                               const float* __restrict__ tl_c1_w,
                                               unsigned short* __restrict__ wp) {
  int cc = blockIdx.x;
  int cotile = blockIdx.y >> 3, chunk = blockIdx.y & 7;
  if (cc == 30) wprep_body<1>(tl_c1_w, wp + (size_t)30*655360, cotile, chunk, threadIdx.x);
  else          wprep_body<5>(conv_w + (size_t)cc*327680, wp + (size_t)cc*655360, cotile, chunk, threadIdx.x);
}

// ---------------- embedding gather + stats partials + inline finalize ----------------
__global__ void k_embed2(const int* __restrict__ inp, const float* __restrict__ emb,
                         float* __restrict__ x, float* __restrict__ statp,
                         float* __restrict__ statd, int* __restrict__ cnt) {
  int bx = blockIdx.x;            // 80 blocks x 120 rows
  int c = threadIdx.x;
  int r0 = bx * 120;
  float s = 0.f, s2 = 0.f;
  for (int r = 0; r < 120; ++r) {
    int row = inp[r0 + r];
    float v = emb[(size_t)row*256 + c];
    x[(size_t)(r0 + r)*256 + c] = v;
    s += v; s2 = fmaf(v, v, s2);
  }
  statp[(size_t)bx*512 + c] = s;
  statp[(size_t)bx*512 + 256 + c] = s2;
  stat_finalize(statp, statd, cnt, 80, c);
}

// ---------------- normalize + ReLU + bf16 hi/lo split (slim: dense stats) ----------------
__global__ __launch_bounds__(256) void k_norm(const float* __restrict__ z,
                      const float* __restrict__ statd,
                      const float* __restrict__ gam, const float* __restrict__ bet,
                      unsigned short* __restrict__ zn) {
  int b = blockIdx.x, chunk = blockIdx.y, sub = blockIdx.z;
  int t = threadIdx.x;
  int srow = t >> 3, fq = t & 7;
  int c0 = chunk*32 + fq*4;
  float4 mu4 = *(const float4*)&statd[c0];
  float4 rs4 = *(const float4*)&statd[256 + c0];
  float4 gm4 = *(const float4*)&gam[b*256 + c0];
  float4 bt4 = *(const float4*)&bet[b*256 + c0];
  float4 sc4, sh4;
  sc4.x = rs4.x*gm4.x; sh4.x = fmaf(-mu4.x, sc4.x, bt4.x);
  sc4.y = rs4.y*gm4.y; sh4.y = fmaf(-mu4.y, sc4.y, bt4.y);
  sc4.z = rs4.z*gm4.z; sh4.z = fmaf(-mu4.z, sc4.z, bt4.z);
  sc4.w = rs4.w*gm4.w; sh4.w = fmaf(-mu4.w, sc4.w, bt4.w);
  unsigned short* zh = zn + ((size_t)b*8 + chunk)*54400 + fq*4;
  unsigned short* zl = zh + 27200;
  const float* zb = z + (size_t)b*600*256 + chunk*32 + fq*4;
  int r0 = sub*68;
  #pragma unroll
  for (int i = 0; i < 3; ++i) {
    int rr = i*32 + srow;
    if (rr < 68) {
      int r = r0 + rr;
      int l = r - 8;
      uint2 vh; vh.x = 0u; vh.y = 0u;
      uint2 vl; vl.x = 0u; vl.y = 0u;
      if (l >= 0 && l < 600) {
        float4 zv = *(const float4*)&zb[(size_t)l*256];
        float v0 = fmaxf(fmaf(zv.x, sc4.x, sh4.x), 0.f);
        float v1 = fmaxf(fmaf(zv.y, sc4.y, sh4.y), 0.f);
        float v2 = fmaxf(fmaf(zv.z, sc4.z, sh4.z), 0.f);
        float v3 = fmaxf(fmaf(zv.w, sc4.w, sh4.w), 0.f);
        unsigned short h0 = f2bf(v0), h1 = f2bf(v1), h2 = f2bf(v2), h3 = f2bf(v3);
        unsigned short e0 = f2bf(v0 - __uint_as_float((unsigned)h0 << 16));
        unsigned short e1 = f2bf(v1 - __uint_as_float((unsigned)h1 << 16));
        unsigned short e2 = f2bf(v2 - __uint_as_float((unsigned)h2 << 16));
        unsigned short e3 = f2bf(v3 - __uint_as_float((unsigned)h3 << 16));
        vh.x = (unsigned)h0 | ((unsigned)h1 << 16);
        vh.y = (unsigned)h2 | ((unsigned)h3 << 16);
        vl.x = (unsigned)e0 | ((unsigned)e1 << 16);
        vl.y = (unsigned)e2 | ((unsigned)e3 << 16);
      }
      *(uint2*)&zh[(size_t)r*40] = vh;
      *(uint2*)&zl[(size_t)r*40] = vl;
    }
  }
}

// ---------------- MFMA dilated conv (R10: REVERT to R6 stage-ahead dbuf) ----------------
// R9 single-buffer = 93us/dispatch vs dbuf ~40 (counter-proven): at 2.5 blocks/CU
// there is no cross-block TLP to hide the per-chunk vmcnt(0) drain — the prefetch
// must be issued a full compute-phase ahead. Ltile=128, grid (80,8), LDS 48KB (3/CU).
template<int TAPS>
__global__ __launch_bounds__(256, 3) void k_convm(const unsigned short* __restrict__ zn,
                        float* __restrict__ out, float* __restrict__ statp,
                        float* __restrict__ statd, int* __restrict__ cnt,
                        const unsigned short* __restrict__ wpc,
                        const float* __restrict__ bias, int dil, int mode) {
  __shared__ __align__(16) unsigned short Zhi[2][6144];   // 12 x 1024B DMA each
  __shared__ __align__(16) unsigned short Zlo[2][6144];
  __shared__ float lsum[32];
  __shared__ float lsq[32];
  int t = threadIdx.x;
  int bx = blockIdx.x;          // 16 b x 5 l-tiles
  int b  = bx / 5;
  int l0 = (bx % 5) * 128;
  int y = blockIdx.y;
  int co0 = y * 32;
  int cobase = (y & 1) * 32;
  int PAD = ((TAPS - 1)/2) * dil;
  int w = t >> 6, lane = t & 63;
  int lsub = (w & 1) * 64, cosub = (w >> 1) * 16;
  int quad = lane >> 4, nlan = lane & 15;
  if (t < 32) { lsum[t] = 0.f; lsq[t] = 0.f; }

  floatx4 acc[4];
  #pragma unroll
  for (int mt = 0; mt < 4; ++mt) acc[mt] = (floatx4){0.f,0.f,0.f,0.f};

  const unsigned short* zbase = zn + (size_t)b*435200 + (size_t)(l0 - PAD + 8)*40 + (size_t)lane*8;
  int ar[4];
  #pragma unroll
  for (int mt = 0; mt < 4; ++mt) ar[mt] = (lsub + mt*16 + nlan) * 40 + quad * 8;

  #define STAGEZ(ch, bf) do {                                             \
    const unsigned short* srcp = zbase + (size_t)(ch)*54400;              \
    for (int i = w; i < 24; i += 4) {                                     \
      int p = (i >= 12) ? 1 : 0;                                          \
      int k = i - p*12;                                                   \
      gld_lds16(srcp + p*27200 + k*512, (p ? Zlo[bf] : Zhi[bf]) + k*512); \
    }                                                                     \
  } while (0)

  STAGEZ(0, 0);
  __syncthreads();

  for (int chunk = 0; chunk < 8; ++chunk) {
    int cb = chunk & 1;
    if (chunk < 7) STAGEZ(chunk + 1, cb ^ 1);   // issue early: hides under compute
    const unsigned short* pch = wpc + (size_t)((y >> 1)*8 + chunk) * (TAPS*4096);
    short8 bh[TAPS], bl[TAPS];
    int cw = (cobase + cosub + nlan)*32 + quad*8;
    #pragma unroll
    for (int tap = 0; tap < TAPS; ++tap) {
      bh[tap] = *(const short8*)(pch + (size_t)(tap*2)*2048 + cw);
      bl[tap] = *(const short8*)(pch + (size_t)(tap*2+1)*2048 + cw);
    }
    #pragma unroll
    for (int tap = 0; tap < TAPS; ++tap) {
      int sh = tap * dil * 40;
      #pragma unroll
      for (int mt = 0; mt < 4; ++mt) {
        short8 ah = *(const short8*)&Zhi[cb][ar[mt] + sh];
        short8 al = *(const short8*)&Zlo[cb][ar[mt] + sh];
        acc[mt] = __builtin_amdgcn_mfma_f32_16x16x32_bf16(ah, bh[tap], acc[mt], 0, 0, 0);
        acc[mt] = __builtin_amdgcn_mfma_f32_16x16x32_bf16(ah, bl[tap], acc[mt], 0, 0, 0);
        acc[mt] = __builtin_amdgcn_mfma_f32_16x16x32_bf16(al, bh[tap], acc[mt], 0, 0, 0);
      }
    }
    __syncthreads();   // drains chunk+1 DMA + this chunk's ds_reads
  }
  #undef STAGEZ

  float bsv = bias[co0 + cosub + nlan];
  float ssum = 0.f, ssq = 0.f;
  #pragma unroll
  for (int mt = 0; mt < 4; ++mt) {
    #pragma unroll
    for (int r = 0; r < 4; ++r) {
      int l = l0 + lsub + mt*16 + quad*4 + r;
      if (l < 600) {
        float v = acc[mt][r] + bsv;
        float* dst = &out[((size_t)(b*600 + l))*256 + co0 + cosub + nlan];
        if (mode) v += *dst;
        *dst = v;
        ssum += v;
        ssq = fmaf(v, v, ssq);
      }
    }
  }
  ssum += __shfl_xor(ssum, 16, 64);
  ssum += __shfl_xor(ssum, 32, 64);
  ssq  += __shfl_xor(ssq, 16, 64);
  ssq  += __shfl_xor(ssq, 32, 64);
  if (quad == 0) {
    atomicAdd(&lsum[cosub + nlan], ssum);   // LDS-scope only
    atomicAdd(&lsq [cosub + nlan], ssq);
  }
  __syncthreads();
  if (t < 32) {
    statp[(size_t)bx*512 + co0 + t] = lsum[t];
    statp[(size_t)bx*512 + 256 + co0 + t] = lsq[t];
  }
  stat_finalize(statp, statd, cnt, 640, t);
}

// ---------------- token-length final 256->1 conv + relu (consumes mu/rs) ----------------
__global__ void k_tl2(const float* __restrict__ z, const float* __restrict__ statd,
                      const float* __restrict__ gam, const float* __restrict__ bet,
                      const float* __restrict__ w2, const float* __restrict__ b2,
                      float* __restrict__ tl) {
  int t = threadIdx.x;
  int row = blockIdx.x * 4 + (t >> 6);
  int lane = t & 63;
  int b = row / 600;
  float4 mu4 = *(const float4*)&statd[lane*4];
  float4 rs4 = *(const float4*)&statd[256 + lane*4];
  float4 gm = *(const float4*)&gam[b*256 + lane*4];
  float4 bt = *(const float4*)&bet[b*256 + lane*4];
  float sc[4], sh[4];
  {
    float mv[4] = {mu4.x, mu4.y, mu4.z, mu4.w};
    float rv[4] = {rs4.x, rs4.y, rs4.z, rs4.w};
    float gv[4] = {gm.x, gm.y, gm.z, gm.w};
    float bv[4] = {bt.x, bt.y, bt.z, bt.w};
    #pragma unroll
    for (int i = 0; i < 4; ++i) {
      sc[i] = rv[i] * gv[i];
      sh[i] = fmaf(-mv[i], sc[i], bv[i]);
    }
  }
  float4 zr = *(const float4*)&z[(size_t)row*256 + lane*4];
  float4 wr = *(const float4*)&w2[lane*4];
  float z0 = fmaxf(fmaf(zr.x, sc[0], sh[0]), 0.f);
  float z1 = fmaxf(fmaf(zr.y, sc[1], sh[1]), 0.f);
  float z2 = fmaxf(fmaf(zr.z, sc[2], sh[2]), 0.f);
  float z3 = fmaxf(fmaf(zr.w, sc[3], sh[3]), 0.f);
  float s = z0*wr.x + z1*wr.y + z2*wr.z + z3*wr.w;
  for (int m = 32; m >= 1; m >>= 1) s += __shfl_xor(s, m, 64);
  if (lane == 0) tl[row] = fmaxf(s + b2[0], 0.f);
}

// ---------------- per-batch cumsum -> ends (output 1) + centers ----------------
__global__ void k_cumsum(const float* __restrict__ tl, float* __restrict__ centers,
                         float* __restrict__ out_len) {
  int b = blockIdx.x; int lane = threadIdx.x;
  float carry = 0.f;
  for (int ch = 0; ch < 10; ++ch) {
    int l = ch*64 + lane;
    float v = (l < 600) ? tl[b*600 + l] : 0.f;
    float s = v;
    #pragma unroll
    for (int off = 1; off < 64; off <<= 1) {
      float n = __shfl_up(s, off, 64);
      if (lane >= off) s += n;
    }
    float ends = carry + s;
    if (l < 600) {
      centers[b*600 + l] = ends - 0.5f*v;
      out_len[b*600 + l] = ends;
    }
    carry = __shfl(ends, 63, 64);
  }
}

// ---------------- fp32 (b,l,c) -> bf16 (b,c,l) transpose, l padded to 640 ----------------
__global__ void k_tobf16(const float* __restrict__ x, unsigned short* __restrict__ fbT) {
  __shared__ unsigned short T[64*66];
  int b = blockIdx.x, lt = blockIdx.y, ct = blockIdx.z;
  int t = threadIdx.x;
  int i4 = t >> 6;
  int j = t & 63;
  #pragma unroll
  for (int r = 0; r < 16; ++r) {
    int li = i4*16 + r;
    int l = lt*64 + li;
    float v = (l < 600) ? x[((size_t)(b*600 + l))*256 + ct*64 + j] : 0.f;
    T[j*66 + li] = f2bf(v);
  }
  __syncthreads();
  int row = t >> 2, seg = (t & 3) * 16;
  unsigned vv[8];
  #pragma unroll
  for (int k = 0; k < 8; ++k)
    vv[k] = *(const unsigned*)&T[row*66 + seg + k*2];
  size_t dsth = ((size_t)(b*256 + ct*64 + row))*640 + lt*64 + seg;
  unsigned* du = (unsigned*)fbT;
  uint4 a; a.x = vv[0]; a.y = vv[1]; a.z = vv[2]; a.w = vv[3];
  uint4 c4; c4.x = vv[4]; c4.y = vv[5]; c4.z = vv[6]; c4.w = vv[7];
  *(uint4*)(du + dsth/2) = a;
  *(uint4*)(du + dsth/2 + 4) = c4;
}

// ---------------- alignment einsum (chunk-skip + coalesced output writes) ----------------
__global__ __launch_bounds__(256, 4) void k_align2(const unsigned short* __restrict__ fbT,
                        const float* __restrict__ centers, float* __restrict__ outp) {
  __shared__ float cen[600];
  __shared__ float mrow[64];
  __shared__ float isum[64];
  __shared__ unsigned short Wt[2][64*80];
  __shared__ float Ost[16*260];
  int b = blockIdx.x;
  int o0 = blockIdx.y * 64;
  int t = threadIdx.x;
  int wv = t >> 6, lane = t & 63;
  for (int i = t; i < 600; i += 256) cen[i] = centers[b*600 + i];
  __syncthreads();
  // phase 1: per-o-row max (exact)
  for (int rr = 0; rr < 16; ++rr) {
    int oi = wv*16 + rr;
    float opos = (float)(o0 + oi);
    float mx = -3.0e38f;
    for (int l = lane; l < 600; l += 64) {
      float d = cen[l] - opos;
      mx = fmaxf(mx, -d*d*0.1f);
    }
    #pragma unroll
    for (int mm = 32; mm >= 1; mm >>= 1) mx = fmaxf(mx, __shfl_xor(mx, mm, 64));
    if (lane == 0) mrow[oi] = mx;
  }
  __syncthreads();
  floatx4 acc[4][4];
  #pragma unroll
  for (int i = 0; i < 4; ++i)
    #pragma unroll
    for (int j = 0; j < 4; ++j)
      acc[i][j] = (floatx4){0.f, 0.f, 0.f, 0.f};
  int quad = lane >> 4;
  int nlan = lane & 15;
  int oi_w = t >> 2;
  int sbase = t & 3;
  float mo = mrow[oi_w];
  float opos_w = (float)(o0 + oi_w);
  float psum = 0.f;
  const unsigned short* srcb = fbT + ((size_t)b*256)*640;
  const unsigned short* fbl = srcb + (size_t)(wv*64 + nlan)*640 + quad*8;

  // active-chunk mask (identical across all 4 waves)
  unsigned actm = 0;
  {
    float opos_l = (float)(o0 + lane);
    float mo_l = mrow[lane];
    for (int ch = 0; ch < 10; ++ch) {
      int lc0 = ch*64;
      int lc1 = (lc0 + 63 < 599) ? lc0 + 63 : 599;
      float clo = cen[lc0], chi = cen[lc1];
      float Do = fmaxf(fmaxf(clo - opos_l, opos_l - chi), 0.f);
      bool near = (fmaf(-Do*Do, 0.1f, -mo_l) >= -80.f);
      if (__ballot(near) != 0ull) actm |= (1u << ch);
    }
  }

  #define STAGE_WT(CH, BF) do {                                              \
    int lcs = (CH) * 64;                                                     \
    _Pragma("unroll")                                                        \
    for (int sidx = 0; sidx < 2; ++sidx) {                                   \
      int seg = sbase + sidx*4;                                              \
      unsigned pk[4];                                                        \
      _Pragma("unroll")                                                      \
      for (int jj = 0; jj < 8; jj += 2) {                                    \
        int li = lcs + seg*8 + jj;                                           \
        float e0 = 0.f, e1 = 0.f;                                            \
        if (li < 600)     { float d = cen[li] - opos_w;     e0 = __expf(-d*d*0.1f - mo); } \
        if (li + 1 < 600) { float d = cen[li + 1] - opos_w; e1 = __expf(-d*d*0.1f - mo); } \
        psum += e0 + e1;                                                     \
        pk[jj>>1] = (unsigned)f2bf(e0) | ((unsigned)f2bf(e1) << 16);         \
      }                                                                      \
      uint4 v; v.x = pk[0]; v.y = pk[1]; v.z = pk[2]; v.w = pk[3];           \
      *(uint4*)&Wt[BF][oi_w*80 + seg*8] = v;                                 \
    }                                                                        \
  } while (0)

  int ch = __ffs(actm) - 1;     // actm != 0 guaranteed (argmax chunk active)
  int buf = 0;
  STAGE_WT(ch, 0);
  __syncthreads();

  while (ch >= 0) {
    unsigned rem = actm & ~((2u << ch) - 1u);   // bits strictly above ch
    int nxt = rem ? (__ffs(rem) - 1) : -1;
    int lc0 = ch * 64;
    short8 bfr[2][4];
    #pragma unroll
    for (int ks = 0; ks < 2; ++ks)
      #pragma unroll
      for (int nt = 0; nt < 4; ++nt)
        bfr[ks][nt] = *(const short8*)(fbl + (size_t)nt*16*640 + lc0 + ks*32);
    if (nxt >= 0) STAGE_WT(nxt, buf ^ 1);
    #pragma unroll
    for (int ks = 0; ks < 2; ++ks) {
      int ko = ks*32 + quad*8;
      short8 af[4];
      #pragma unroll
      for (int mt = 0; mt < 4; ++mt)
        af[mt] = *(const short8*)&Wt[buf][(mt*16 + nlan)*80 + ko];
      #pragma unroll
      for (int mt = 0; mt < 4; ++mt)
        #pragma unroll
        for (int nt = 0; nt < 4; ++nt)
          acc[mt][nt] = __builtin_amdgcn_mfma_f32_16x16x32_bf16(af[mt], bfr[ks][nt], acc[mt][nt], 0, 0, 0);
    }
    __syncthreads();   // stage(nxt) visible; reads of buf done before re-stage
    ch = nxt; buf ^= 1;
  }
  #undef STAGE_WT

  psum += __shfl_xor(psum, 1, 64);
  psum += __shfl_xor(psum, 2, 64);
  if ((t & 3) == 0) isum[oi_w] = 1.0f / psum;
  __syncthreads();

  // coalesced epilogue: 4 slabs of 16 o-rows via LDS
  int orow = t >> 4, oseg = (t & 15) * 16;
  #pragma unroll
  for (int mt = 0; mt < 4; ++mt) {
    if (mt > 0) __syncthreads();       // Ost free from previous slab
    #pragma unroll
    for (int r = 0; r < 4; ++r) {
      float sc = isum[mt*16 + quad*4 + r];
      #pragma unroll
      for (int nt = 0; nt < 4; ++nt)
        Ost[(quad*4 + r)*260 + wv*64 + nt*16 + nlan] = acc[mt][nt][r] * sc;
    }
    __syncthreads();
    int o = o0 + mt*16 + orow;
    if (o < 6000) {
      const float* src = &Ost[orow*260 + oseg];
      float* dst = &outp[((size_t)b*6000 + o)*256 + oseg];
      #pragma unroll
      for (int q = 0; q < 4; ++q)
        *(float4*)(dst + q*4) = *(const float4*)(src + q*4);
    }
  }
}

extern "C" void kernel_launch(void* const* d_in, const int* in_sizes, int n_in,
                              void* d_out, int out_size, void* d_ws, size_t ws_size,
                              hipStream_t stream) {
  const int*   inputs = (const int*)  d_in[0];
  const float* spk    = (const float*)d_in[1];
  const float* noise  = (const float*)d_in[2];
  const float* emb    = (const float*)d_in[3];
  const float* conv_w = (const float*)d_in[4];
  const float* conv_b = (const float*)d_in[5];
  const float* g_w    = (const float*)d_in[6];
  const float* g_b    = (const float*)d_in[7];
  const float* b_w    = (const float*)d_in[8];
  const float* b_b    = (const float*)d_in[9];
  const float* tl_g_w = (const float*)d_in[10];
  const float* tl_g_b = (const float*)d_in[11];
  const float* tl_b_w = (const float*)d_in[12];
  const float* tl_b_b = (const float*)d_in[13];
  const float* tl_c1_w = (const float*)d_in[14];
  const float* tl_c1_b = (const float*)d_in[15];
  const float* tl_c2_w = (const float*)d_in[16];
  const float* tl_c2_b = (const float*)d_in[17];
  float* out = (float*)d_out;

  float* ws = (float*)d_ws;
  float* x       = ws;                 // 2457600
  float* A       = x + 2457600;        // 2457600
  float* Bf      = A + 2457600;        // 2457600 (reused as fbT at the end)
  float* gammas  = Bf + 2457600;       // 131072
  float* betas   = gammas + 131072;    // 131072
  float* statp   = betas + 131072;     // 80 x 512 partials (region reserves 81920)
  float* statd   = statp + 81920;      // dense mu/rs = 512
  int*   cnt     = (int*)(statd + 512);// ticket counter (16 floats reserved)
  float* tl      = statd + 528;        // 9600
  float* cen     = tl + 9600;          // 9600
  unsigned short* wp = (unsigned short*)(cen + 9600);   // ~40.6 MB
  unsigned short* Zn = wp + (size_t)31*655360;          // 13.9 MB
  unsigned short* fbT = (unsigned short*)Bf;
  float* gpart = (float*)Zn;           // gb partials (time-disjoint with Zn)
  float* bpart = gpart + 1048576;

  k_zeroi<<<dim3(1), dim3(64), 0, stream>>>(cnt);
  k_wprep<<<dim3(31, 32), dim3(256), 0, stream>>>(conv_w, tl_c1_w, wp);
  k_gb_part<<<dim3(32, 8), dim3(256), 0, stream>>>(spk, noise, g_w, b_w,
      tl_g_w, tl_b_w, gpart, bpart);
  k_gb_red<<<dim3(512), dim3(256), 0, stream>>>(gpart, bpart, g_b, b_b,
      tl_g_b, tl_b_b, gammas, betas);
  k_embed2<<<dim3(80), dim3(256), 0, stream>>>(inputs, emb, x, statp, statd, cnt);

  const int dils[3] = {1, 2, 4};
  for (int blk = 0; blk < 10; ++blk) {
    const float* srcs[3] = {x, A, Bf};
    float*       dsts[3] = {A, Bf, x};   // ping-pong; never in-place (R2 race)
    for (int j = 0; j < 3; ++j) {
      int idx = blk*3 + j;
      int mode = (j == 2) ? 1 : 0;
      k_norm<<<dim3(16, 8, 10), dim3(256), 0, stream>>>(srcs[j],
          statd, gammas + idx*4096, betas + idx*4096, Zn);
      k_convm<5><<<dim3(80, 8), dim3(256), 0, stream>>>(Zn, dsts[j],
          statp, statd, cnt, wp + (size_t)idx*655360, conv_b + idx*256, dils[j], mode);
    }
  }
  // token-length head
  k_norm<<<dim3(16, 8, 10), dim3(256), 0, stream>>>(x,
      statd, gammas + 30*4096, betas + 30*4096, Zn);
  k_convm<1><<<dim3(80, 8), dim3(256), 0, stream>>>(Zn, A,
      statp, statd, cnt, wp + (size_t)30*655360, tl_c1_b, 1, 0);
  k_tl2<<<dim3(2400), dim3(256), 0, stream>>>(A, statd,
      gammas + 31*4096, betas + 31*4096, tl_c2_w, tl_c2_b, tl);
  k_cumsum<<<dim3(16), dim3(64), 0, stream>>>(tl, cen, out + 24576000);
  // alignment einsum (bf16 MFMA)
  k_tobf16<<<dim3(16, 10, 4), dim3(256), 0, stream>>>(x, fbT);
  k_align2<<<dim3(16, 94), dim3(256), 0, stream>>>(fbT, cen, out);
}

// Round 11
// 1545.227 us; speedup vs baseline: 2.1276x; 2.1276x over previous
//
#include <hip/hip_runtime.h>
#include <math.h>
#include <stdint.h>

#define EPSv 1e-5f

typedef short short8 __attribute__((ext_vector_type(8)));
typedef float floatx4 __attribute__((ext_vector_type(4)));

__device__ __forceinline__ unsigned short f2bf(float x) {
  unsigned u = __float_as_uint(x);
  unsigned r = (u + 0x7fffu + ((u >> 16) & 1u)) >> 16;
  return (unsigned short)r;
}

// global->LDS direct DMA, 16B/lane (explicit address spaces; CK cast pattern).
__device__ __forceinline__ void gld_lds16(const void* g, void* l) {
  __builtin_amdgcn_global_load_lds(
      (const __attribute__((address_space(1))) unsigned*)(uintptr_t)g,
      (__attribute__((address_space(3))) unsigned*)(uintptr_t)l,
      16, 0, 0);
}

// ---------------- gamma/beta via k-slice partials ----------------
__global__ __launch_bounds__(256) void k_gb_part(const float* __restrict__ spk,
                             const float* __restrict__ noise,
                             const float* __restrict__ g_w, const float* __restrict__ b_w,
                             const float* __restrict__ tl_g_w, const float* __restrict__ tl_b_w,
                             float* __restrict__ gpart, float* __restrict__ bpart) {
  __shared__ float condl[16][32];
  int i = blockIdx.x, ks = blockIdx.y;
  int t = threadIdx.x;
  for (int idx = t; idx < 512; idx += 256) {
    int b = idx >> 5, kk = idx & 31;
    int k = ks*32 + kk;
    condl[b][kk] = (k < 128) ? spk[b*128 + k] : noise[b*128 + k - 128];
  }
  __syncthreads();
  const float *gw, *bw;
  if (i < 30) { gw = g_w + (size_t)i*65536; bw = b_w + (size_t)i*65536; }
  else        { gw = tl_g_w + (size_t)(i-30)*65536; bw = tl_b_w + (size_t)(i-30)*65536; }
  int co = t;
  float g[16], bt[16];
  #pragma unroll
  for (int b = 0; b < 16; ++b) { g[b] = 0.f; bt[b] = 0.f; }
  for (int kk = 0; kk < 32; ++kk) {
    float gwv = gw[(size_t)(ks*32 + kk)*256 + co];
    float bwv = bw[(size_t)(ks*32 + kk)*256 + co];
    #pragma unroll
    for (int b = 0; b < 16; ++b) {
      float cv = condl[b][kk];
      g[b]  = fmaf(cv, gwv, g[b]);
      bt[b] = fmaf(cv, bwv, bt[b]);
    }
  }
  size_t base = ((size_t)(i*8 + ks)*16)*256 + co;
  #pragma unroll
  for (int b = 0; b < 16; ++b) {
    gpart[base + (size_t)b*256] = g[b];
    bpart[base + (size_t)b*256] = bt[b];
  }
}

__global__ void k_gb_red(const float* __restrict__ gpart, const float* __restrict__ bpart,
                         const float* __restrict__ g_b, const float* __restrict__ b_b,
                         const float* __restrict__ tl_g_b, const float* __restrict__ tl_b_b,
                         float* __restrict__ gammas, float* __restrict__ betas) {
  int idx = blockIdx.x*256 + threadIdx.x;    // 0..131071
  int i = idx >> 12, rem = idx & 4095;
  int co = rem & 255;
  float gs = 0.f, bs = 0.f;
  #pragma unroll
  for (int ks = 0; ks < 8; ++ks) {
    size_t p = ((size_t)(i*8 + ks) << 12) + rem;
    gs += gpart[p];
    bs += bpart[p];
  }
  float gbias = (i < 30) ? g_b[i*256 + co] : tl_g_b[(i-30)*256 + co];
  float bbias = (i < 30) ? b_b[i*256 + co] : tl_b_b[(i-30)*256 + co];
  gammas[idx] = 1.0f + gs + gbias;
  betas [idx] = bs + bbias;
}

// ---------------- weight prepack ----------------
template<int TAPS>
__device__ __forceinline__ void wprep_body(const float* __restrict__ src,
                                           unsigned short* __restrict__ dst,
                                           int cotile, int chunk, int t) {
  int cow = t >> 2, ci8 = (t & 3) * 8;
  const float* s0 = src + ((size_t)(cotile*64 + cow)*256 + chunk*32 + ci8)*TAPS;
  float v[8*TAPS];
  #pragma unroll
  for (int i = 0; i < 8*TAPS; ++i) v[i] = s0[i];
  unsigned short* dblk = dst + (size_t)cotile*(8*TAPS*4096) + (size_t)chunk*(TAPS*4096);
  #pragma unroll
  for (int tap = 0; tap < TAPS; ++tap) {
    unsigned hi2[4], lo2[4];
    #pragma unroll
    for (int jj = 0; jj < 4; ++jj) {
      float a = v[(jj*2+0)*TAPS + tap], b = v[(jj*2+1)*TAPS + tap];
      unsigned short ha = f2bf(a), hb = f2bf(b);
      unsigned short la = f2bf(a - __uint_as_float((unsigned)ha << 16));
      unsigned short lb = f2bf(b - __uint_as_float((unsigned)hb << 16));
      hi2[jj] = (unsigned)ha | ((unsigned)hb << 16);
      lo2[jj] = (unsigned)la | ((unsigned)lb << 16);
    }
    uint4 H; H.x = hi2[0]; H.y = hi2[1]; H.z = hi2[2]; H.w = hi2[3];
    uint4 L; L.x = lo2[0]; L.y = lo2[1]; L.z = lo2[2]; L.w = lo2[3];
    *(uint4*)(dblk + (size_t)(tap*2)*2048 + cow*32 + ci8) = H;
    *(uint4*)(dblk + (size_t)(tap*2+1)*2048 + cow*32 + ci8) = L;
  }
}

__global__ __launch_bounds__(256) void k_wprep(const float* __restrict__ conv_w,
                                               const float* __restrict__ tl_c1_w,
                                               unsigned short* __restrict__ wp) {
  int cc = blockIdx.x;
  int cotile = blockIdx.y >> 3, chunk = blockIdx.y & 7;
  if (cc == 30) wprep_body<1>(tl_c1_w, wp + (size_t)30*655360, cotile, chunk, threadIdx.x);
  else          wprep_body<5>(conv_w + (size_t)cc*327680, wp + (size_t)cc*655360, cotile, chunk, threadIdx.x);
}

// ---------------- embedding gather + 80 per-block stats partials (NO fence/ticket) ----------------
__global__ void k_embed2(const int* __restrict__ inp, const float* __restrict__ emb,
                         float* __restrict__ x, float* __restrict__ statp) {
  int bx = blockIdx.x;            // 80 blocks x 120 rows
  int c = threadIdx.x;
  int r0 = bx * 120;
  float s = 0.f, s2 = 0.f;
  for (int r = 0; r < 120; ++r) {
    int row = inp[r0 + r];
    float v = emb[(size_t)row*256 + c];
    x[(size_t)(r0 + r)*256 + c] = v;
    s += v; s2 = fmaf(v, v, s2);
  }
  statp[(size_t)bx*512 + c] = s;
  statp[(size_t)bx*512 + 256 + c] = s2;
}

// ---------------- normalize + ReLU + bf16 hi/lo split (R8: inline 80-partial reduce) ----------------
// Zn[b][chunk(8)][plane(2)][row 0..679][40 halves]; row r <-> l = r-8; OOB rows = 0.
// R10 post-mortem: per-block __threadfence() ticket (R9/R10) = device fence = L2
// writeback per block = ~55us/dispatch. Reverted to R8's fence-free inline reduce.
__global__ __launch_bounds__(256) void k_norm(const float* __restrict__ z,
                      const float* __restrict__ statp,
                      const float* __restrict__ gam, const float* __restrict__ bet,
                      unsigned short* __restrict__ zn) {
  __shared__ float s_sc[32];
  __shared__ float s_sh[32];
  __shared__ float red[2][32][8];
  int b = blockIdx.x, chunk = blockIdx.y, sub = blockIdx.z;
  int t = threadIdx.x;
  {
    int ch = t >> 3, g = t & 7;
    int c = chunk*32 + ch;
    float s = 0.f, s2 = 0.f;
    for (int p = g; p < 80; p += 8) {
      s  += statp[(size_t)p*512 + c];
      s2 += statp[(size_t)p*512 + 256 + c];
    }
    red[0][ch][g] = s; red[1][ch][g] = s2;
  }
  __syncthreads();
  if (t < 32) {
    float s = 0.f, s2 = 0.f;
    #pragma unroll
    for (int g = 0; g < 8; ++g) { s += red[0][t][g]; s2 += red[1][t][g]; }
    int c = chunk*32 + t;
    float mu = s * (1.0f/9600.0f);
    float var = s2 * (1.0f/9600.0f) - mu*mu;
    float rs = rsqrtf(var + EPSv);
    float scale = rs * gam[b*256 + c];
    s_sc[t] = scale;
    s_sh[t] = fmaf(-mu, scale, bet[b*256 + c]);
  }
  __syncthreads();
  int srow = t >> 3, fq = t & 7;
  float4 sc4 = *(const float4*)&s_sc[fq*4];
  float4 sh4 = *(const float4*)&s_sh[fq*4];
  unsigned short* zh = zn + ((size_t)b*8 + chunk)*54400 + fq*4;
  unsigned short* zl = zh + 27200;
  const float* zb = z + (size_t)b*600*256 + chunk*32 + fq*4;
  int r0 = sub*68;
  #pragma unroll
  for (int i = 0; i < 3; ++i) {
    int rr = i*32 + srow;
    if (rr < 68) {
      int r = r0 + rr;
      int l = r - 8;
      uint2 vh; vh.x = 0u; vh.y = 0u;
      uint2 vl; vl.x = 0u; vl.y = 0u;
      if (l >= 0 && l < 600) {
        float4 zv = *(const float4*)&zb[(size_t)l*256];
        float v0 = fmaxf(fmaf(zv.x, sc4.x, sh4.x), 0.f);
        float v1 = fmaxf(fmaf(zv.y, sc4.y, sh4.y), 0.f);
        float v2 = fmaxf(fmaf(zv.z, sc4.z, sh4.z), 0.f);
        float v3 = fmaxf(fmaf(zv.w, sc4.w, sh4.w), 0.f);
        unsigned short h0 = f2bf(v0), h1 = f2bf(v1), h2 = f2bf(v2), h3 = f2bf(v3);
        unsigned short e0 = f2bf(v0 - __uint_as_float((unsigned)h0 << 16));
        unsigned short e1 = f2bf(v1 - __uint_as_float((unsigned)h1 << 16));
        unsigned short e2 = f2bf(v2 - __uint_as_float((unsigned)h2 << 16));
        unsigned short e3 = f2bf(v3 - __uint_as_float((unsigned)h3 << 16));
        vh.x = (unsigned)h0 | ((unsigned)h1 << 16);
        vh.y = (unsigned)h2 | ((unsigned)h3 << 16);
        vl.x = (unsigned)e0 | ((unsigned)e1 << 16);
        vl.y = (unsigned)e2 | ((unsigned)e3 << 16);
      }
      *(uint2*)&zh[(size_t)r*40] = vh;
      *(uint2*)&zl[(size_t)r*40] = vl;
    }
  }
}

// ---------------- MFMA dilated conv (R8 structure: stage-ahead dbuf, NO fence) ----------------
// Ltile=128, grid (80,8) = 640 blocks. 4 waves: 2(l64) x 2(co16); acc[4], 60 MFMA/chunk.
// LDS 48KB dbuf, 3 blocks/CU. Epilogue: plain per-block partial stores only.
template<int TAPS>
__global__ __launch_bounds__(256, 3) void k_convm(const unsigned short* __restrict__ zn,
                        float* __restrict__ out, float* __restrict__ statp,
                        const unsigned short* __restrict__ wpc,
                        const float* __restrict__ bias, int dil, int mode) {
  __shared__ __align__(16) unsigned short Zhi[2][6144];   // 12 x 1024B DMA each
  __shared__ __align__(16) unsigned short Zlo[2][6144];
  __shared__ float lsum[32];
  __shared__ float lsq[32];
  int t = threadIdx.x;
  int bx = blockIdx.x;          // 16 b x 5 l-tiles
  int b  = bx / 5;
  int l0 = (bx % 5) * 128;
  int y = blockIdx.y;
  int co0 = y * 32;
  int cobase = (y & 1) * 32;
  int PAD = ((TAPS - 1)/2) * dil;
  int w = t >> 6, lane = t & 63;
  int lsub = (w & 1) * 64, cosub = (w >> 1) * 16;
  int quad = lane >> 4, nlan = lane & 15;
  if (t < 32) { lsum[t] = 0.f; lsq[t] = 0.f; }

  floatx4 acc[4];
  #pragma unroll
  for (int mt = 0; mt < 4; ++mt) acc[mt] = (floatx4){0.f,0.f,0.f,0.f};

  const unsigned short* zbase = zn + (size_t)b*435200 + (size_t)(l0 - PAD + 8)*40 + (size_t)lane*8;
  int ar[4];
  #pragma unroll
  for (int mt = 0; mt < 4; ++mt) ar[mt] = (lsub + mt*16 + nlan) * 40 + quad * 8;

  #define STAGEZ(ch, bf) do {                                             \
    const unsigned short* srcp = zbase + (size_t)(ch)*54400;              \
    for (int i = w; i < 24; i += 4) {                                     \
      int p = (i >= 12) ? 1 : 0;                                          \
      int k = i - p*12;                                                   \
      gld_lds16(srcp + p*27200 + k*512, (p ? Zlo[bf] : Zhi[bf]) + k*512); \
    }                                                                     \
  } while (0)

  STAGEZ(0, 0);
  __syncthreads();

  for (int chunk = 0; chunk < 8; ++chunk) {
    int cb = chunk & 1;
    if (chunk < 7) STAGEZ(chunk + 1, cb ^ 1);   // issue early: hides under compute
    const unsigned short* pch = wpc + (size_t)((y >> 1)*8 + chunk) * (TAPS*4096);
    short8 bh[TAPS], bl[TAPS];
    int cw = (cobase + cosub + nlan)*32 + quad*8;
    #pragma unroll
    for (int tap = 0; tap < TAPS; ++tap) {
      bh[tap] = *(const short8*)(pch + (size_t)(tap*2)*2048 + cw);
      bl[tap] = *(const short8*)(pch + (size_t)(tap*2+1)*2048 + cw);
    }
    #pragma unroll
    for (int tap = 0; tap < TAPS; ++tap) {
      int sh = tap * dil * 40;
      #pragma unroll
      for (int mt = 0; mt < 4; ++mt) {
        short8 ah = *(const short8*)&Zhi[cb][ar[mt] + sh];
        short8 al = *(const short8*)&Zlo[cb][ar[mt] + sh];
        acc[mt] = __builtin_amdgcn_mfma_f32_16x16x32_bf16(ah, bh[tap], acc[mt], 0, 0, 0);
        acc[mt] = __builtin_amdgcn_mfma_f32_16x16x32_bf16(ah, bl[tap], acc[mt], 0, 0, 0);
        acc[mt] = __builtin_amdgcn_mfma_f32_16x16x32_bf16(al, bh[tap], acc[mt], 0, 0, 0);
      }
    }
    __syncthreads();   // drains chunk+1 DMA + this chunk's ds_reads
  }
  #undef STAGEZ

  float bsv = bias[co0 + cosub + nlan];
  float ssum = 0.f, ssq = 0.f;
  #pragma unroll
  for (int mt = 0; mt < 4; ++mt) {
    #pragma unroll
    for (int r = 0; r < 4; ++r) {
      int l = l0 + lsub + mt*16 + quad*4 + r;
      if (l < 600) {
        float v = acc[mt][r] + bsv;
        float* dst = &out[((size_t)(b*600 + l))*256 + co0 + cosub + nlan];
        if (mode) v += *dst;
        *dst = v;
        ssum += v;
        ssq = fmaf(v, v, ssq);
      }
    }
  }
  ssum += __shfl_xor(ssum, 16, 64);
  ssum += __shfl_xor(ssum, 32, 64);
  ssq  += __shfl_xor(ssq, 16, 64);
  ssq  += __shfl_xor(ssq, 32, 64);
  if (quad == 0) {
    atomicAdd(&lsum[cosub + nlan], ssum);   // LDS-scope only
    atomicAdd(&lsq [cosub + nlan], ssq);
  }
  __syncthreads();
  if (t < 32) {
    statp[(size_t)bx*512 + co0 + t] = lsum[t];
    statp[(size_t)bx*512 + 256 + co0 + t] = lsq[t];
  }
}

// ---------------- reduce stats partials -> dense 512 raw sums (for k_tl2) ----------------
__global__ void k_statred(const float* __restrict__ sp, float* __restrict__ dst) {
  int idx = blockIdx.x*256 + threadIdx.x;
  float s = 0.f;
  for (int p = 0; p < 80; ++p) s += sp[(size_t)p*512 + idx];
  dst[idx] = s;
}

// ---------------- token-length final 256->1 conv + relu ----------------
__global__ void k_tl2(const float* __restrict__ z, const float* __restrict__ stat,
                      const float* __restrict__ gam, const float* __restrict__ bet,
                      const float* __restrict__ w2, const float* __restrict__ b2,
                      float* __restrict__ tl) {
  int t = threadIdx.x;
  int row = blockIdx.x * 4 + (t >> 6);
  int lane = t & 63;
  int b = row / 600;
  float4 s1 = *(const float4*)&stat[lane*4];
  float4 s2 = *(const float4*)&stat[256 + lane*4];
  float4 gm = *(const float4*)&gam[b*256 + lane*4];
  float4 bt = *(const float4*)&bet[b*256 + lane*4];
  float sc[4], sh[4];
  {
    float sv[4] = {s1.x, s1.y, s1.z, s1.w};
    float qv[4] = {s2.x, s2.y, s2.z, s2.w};
    float gv[4] = {gm.x, gm.y, gm.z, gm.w};
    float bv[4] = {bt.x, bt.y, bt.z, bt.w};
    #pragma unroll
    for (int i = 0; i < 4; ++i) {
      float mu = sv[i] * (1.0f/9600.0f);
      float var = qv[i] * (1.0f/9600.0f) - mu*mu;
      float rs = rsqrtf(var + EPSv);
      sc[i] = rs * gv[i];
      sh[i] = fmaf(-mu, sc[i], bv[i]);
    }
  }
  float4 zr = *(const float4*)&z[(size_t)row*256 + lane*4];
  float4 wr = *(const float4*)&w2[lane*4];
  float z0 = fmaxf(fmaf(zr.x, sc[0], sh[0]), 0.f);
  float z1 = fmaxf(fmaf(zr.y, sc[1], sh[1]), 0.f);
  float z2 = fmaxf(fmaf(zr.z, sc[2], sh[2]), 0.f);
  float z3 = fmaxf(fmaf(zr.w, sc[3], sh[3]), 0.f);
  float s = z0*wr.x + z1*wr.y + z2*wr.z + z3*wr.w;
  for (int m = 32; m >= 1; m >>= 1) s += __shfl_xor(s, m, 64);
  if (lane == 0) tl[row] = fmaxf(s + b2[0], 0.f);
}

// ---------------- per-batch cumsum -> ends (output 1) + centers ----------------
__global__ void k_cumsum(const float* __restrict__ tl, float* __restrict__ centers,
                         float* __restrict__ out_len) {
  int b = blockIdx.x; int lane = threadIdx.x;
  float carry = 0.f;
  for (int ch = 0; ch < 10; ++ch) {
    int l = ch*64 + lane;
    float v = (l < 600) ? tl[b*600 + l] : 0.f;
    float s = v;
    #pragma unroll
    for (int off = 1; off < 64; off <<= 1) {
      float n = __shfl_up(s, off, 64);
      if (lane >= off) s += n;
    }
    float ends = carry + s;
    if (l < 600) {
      centers[b*600 + l] = ends - 0.5f*v;
      out_len[b*600 + l] = ends;
    }
    carry = __shfl(ends, 63, 64);
  }
}

// ---------------- fp32 (b,l,c) -> bf16 (b,c,l) transpose, l padded to 640 ----------------
__global__ void k_tobf16(const float* __restrict__ x, unsigned short* __restrict__ fbT) {
  __shared__ unsigned short T[64*66];
  int b = blockIdx.x, lt = blockIdx.y, ct = blockIdx.z;
  int t = threadIdx.x;
  int i4 = t >> 6;
  int j = t & 63;
  #pragma unroll
  for (int r = 0; r < 16; ++r) {
    int li = i4*16 + r;
    int l = lt*64 + li;
    float v = (l < 600) ? x[((size_t)(b*600 + l))*256 + ct*64 + j] : 0.f;
    T[j*66 + li] = f2bf(v);
  }
  __syncthreads();
  int row = t >> 2, seg = (t & 3) * 16;
  unsigned vv[8];
  #pragma unroll
  for (int k = 0; k < 8; ++k)
    vv[k] = *(const unsigned*)&T[row*66 + seg + k*2];
  size_t dsth = ((size_t)(b*256 + ct*64 + row))*640 + lt*64 + seg;
  unsigned* du = (unsigned*)fbT;
  uint4 a; a.x = vv[0]; a.y = vv[1]; a.z = vv[2]; a.w = vv[3];
  uint4 c4; c4.x = vv[4]; c4.y = vv[5]; c4.z = vv[6]; c4.w = vv[7];
  *(uint4*)(du + dsth/2) = a;
  *(uint4*)(du + dsth/2 + 4) = c4;
}

// ---------------- alignment einsum (chunk-skip + coalesced output writes) ----------------
__global__ __launch_bounds__(256, 4) void k_align2(const unsigned short* __restrict__ fbT,
                        const float* __restrict__ centers, float* __restrict__ outp) {
  __shared__ float cen[600];
  __shared__ float mrow[64];
  __shared__ float isum[64];
  __shared__ unsigned short Wt[2][64*80];
  __shared__ float Ost[16*260];
  int b = blockIdx.x;
  int o0 = blockIdx.y * 64;
  int t = threadIdx.x;
  int wv = t >> 6, lane = t & 63;
  for (int i = t; i < 600; i += 256) cen[i] = centers[b*600 + i];
  __syncthreads();
  // phase 1: per-o-row max (exact)
  for (int rr = 0; rr < 16; ++rr) {
    int oi = wv*16 + rr;
    float opos = (float)(o0 + oi);
    float mx = -3.0e38f;
    for (int l = lane; l < 600; l += 64) {
      float d = cen[l] - opos;
      mx = fmaxf(mx, -d*d*0.1f);
    }
    #pragma unroll
    for (int mm = 32; mm >= 1; mm >>= 1) mx = fmaxf(mx, __shfl_xor(mx, mm, 64));
    if (lane == 0) mrow[oi] = mx;
  }
  __syncthreads();
  floatx4 acc[4][4];
  #pragma unroll
  for (int i = 0; i < 4; ++i)
    #pragma unroll
    for (int j = 0; j < 4; ++j)
      acc[i][j] = (floatx4){0.f, 0.f, 0.f, 0.f};
  int quad = lane >> 4;
  int nlan = lane & 15;
  int oi_w = t >> 2;
  int sbase = t & 3;
  float mo = mrow[oi_w];
  float opos_w = (float)(o0 + oi_w);
  float psum = 0.f;
  const unsigned short* srcb = fbT + ((size_t)b*256)*640;
  const unsigned short* fbl = srcb + (size_t)(wv*64 + nlan)*640 + quad*8;

  // active-chunk mask (identical across all 4 waves)
  unsigned actm = 0;
  {
    float opos_l = (float)(o0 + lane);
    float mo_l = mrow[lane];
    for (int ch = 0; ch < 10; ++ch) {
      int lc0 = ch*64;
      int lc1 = (lc0 + 63 < 599) ? lc0 + 63 : 599;
      float clo = cen[lc0], chi = cen[lc1];
      float Do = fmaxf(fmaxf(clo - opos_l, opos_l - chi), 0.f);
      bool near = (fmaf(-Do*Do, 0.1f, -mo_l) >= -80.f);
      if (__ballot(near) != 0ull) actm |= (1u << ch);
    }
  }

  #define STAGE_WT(CH, BF) do {                                              \
    int lcs = (CH) * 64;                                                     \
    _Pragma("unroll")                                                        \
    for (int sidx = 0; sidx < 2; ++sidx) {                                   \
      int seg = sbase + sidx*4;                                              \
      unsigned pk[4];                                                        \
      _Pragma("unroll")                                                      \
      for (int jj = 0; jj < 8; jj += 2) {                                    \
        int li = lcs + seg*8 + jj;                                           \
        float e0 = 0.f, e1 = 0.f;                                            \
        if (li < 600)     { float d = cen[li] - opos_w;     e0 = __expf(-d*d*0.1f - mo); } \
        if (li + 1 < 600) { float d = cen[li + 1] - opos_w; e1 = __expf(-d*d*0.1f - mo); } \
        psum += e0 + e1;                                                     \
        pk[jj>>1] = (unsigned)f2bf(e0) | ((unsigned)f2bf(e1) << 16);         \
      }                                                                      \
      uint4 v; v.x = pk[0]; v.y = pk[1]; v.z = pk[2]; v.w = pk[3];           \
      *(uint4*)&Wt[BF][oi_w*80 + seg*8] = v;                                 \
    }                                                                        \
  } while (0)

  int ch = __ffs(actm) - 1;     // actm != 0 guaranteed (argmax chunk active)
  int buf = 0;
  STAGE_WT(ch, 0);
  __syncthreads();

  while (ch >= 0) {
    unsigned rem = actm & ~((2u << ch) - 1u);   // bits strictly above ch
    int nxt = rem ? (__ffs(rem) - 1) : -1;
    int lc0 = ch * 64;
    short8 bfr[2][4];
    #pragma unroll
    for (int ks = 0; ks < 2; ++ks)
      #pragma unroll
      for (int nt = 0; nt < 4; ++nt)
        bfr[ks][nt] = *(const short8*)(fbl + (size_t)nt*16*640 + lc0 + ks*32);
    if (nxt >= 0) STAGE_WT(nxt, buf ^ 1);
    #pragma unroll
    for (int ks = 0; ks < 2; ++ks) {
      int ko = ks*32 + quad*8;
      short8 af[4];
      #pragma unroll
      for (int mt = 0; mt < 4; ++mt)
        af[mt] = *(const short8*)&Wt[buf][(mt*16 + nlan)*80 + ko];
      #pragma unroll
      for (int mt = 0; mt < 4; ++mt)
        #pragma unroll
        for (int nt = 0; nt < 4; ++nt)
          acc[mt][nt] = __builtin_amdgcn_mfma_f32_16x16x32_bf16(af[mt], bfr[ks][nt], acc[mt][nt], 0, 0, 0);
    }
    __syncthreads();   // stage(nxt) visible; reads of buf done before re-stage
    ch = nxt; buf ^= 1;
  }
  #undef STAGE_WT

  psum += __shfl_xor(psum, 1, 64);
  psum += __shfl_xor(psum, 2, 64);
  if ((t & 3) == 0) isum[oi_w] = 1.0f / psum;
  __syncthreads();

  // coalesced epilogue: 4 slabs of 16 o-rows via LDS
  int orow = t >> 4, oseg = (t & 15) * 16;
  #pragma unroll
  for (int mt = 0; mt < 4; ++mt) {
    if (mt > 0) __syncthreads();       // Ost free from previous slab
    #pragma unroll
    for (int r = 0; r < 4; ++r) {
      float sc = isum[mt*16 + quad*4 + r];
      #pragma unroll
      for (int nt = 0; nt < 4; ++nt)
        Ost[(quad*4 + r)*260 + wv*64 + nt*16 + nlan] = acc[mt][nt][r] * sc;
    }
    __syncthreads();
    int o = o0 + mt*16 + orow;
    if (o < 6000) {
      const float* src = &Ost[orow*260 + oseg];
      float* dst = &outp[((size_t)b*6000 + o)*256 + oseg];
      #pragma unroll
      for (int q = 0; q < 4; ++q)
        *(float4*)(dst + q*4) = *(const float4*)(src + q*4);
    }
  }
}

extern "C" void kernel_launch(void* const* d_in, const int* in_sizes, int n_in,
                              void* d_out, int out_size, void* d_ws, size_t ws_size,
                              hipStream_t stream) {
  const int*   inputs = (const int*)  d_in[0];
  const float* spk    = (const float*)d_in[1];
  const float* noise  = (const float*)d_in[2];
  const float* emb    = (const float*)d_in[3];
  const float* conv_w = (const float*)d_in[4];
  const float* conv_b = (const float*)d_in[5];
  const float* g_w    = (const float*)d_in[6];
  const float* g_b    = (const float*)d_in[7];
  const float* b_w    = (const float*)d_in[8];
  const float* b_b    = (const float*)d_in[9];
  const float* tl_g_w = (const float*)d_in[10];
  const float* tl_g_b = (const float*)d_in[11];
  const float* tl_b_w = (const float*)d_in[12];
  const float* tl_b_b = (const float*)d_in[13];
  const float* tl_c1_w = (const float*)d_in[14];
  const float* tl_c1_b = (const float*)d_in[15];
  const float* tl_c2_w = (const float*)d_in[16];
  const float* tl_c2_b = (const float*)d_in[17];
  float* out = (float*)d_out;

  float* ws = (float*)d_ws;
  float* x       = ws;                 // 2457600
  float* A       = x + 2457600;        // 2457600
  float* Bf      = A + 2457600;        // 2457600 (reused as fbT at the end)
  float* gammas  = Bf + 2457600;       // 131072
  float* betas   = gammas + 131072;    // 131072
  float* statp   = betas + 131072;     // 80 x 512 partials (region reserves 81920)
  float* stat31  = statp + 81920;      // dense 512
  float* tl      = stat31 + 512;       // 9600
  float* cen     = tl + 9600;          // 9600
  unsigned short* wp = (unsigned short*)(cen + 9600);   // ~40.6 MB
  unsigned short* Zn = wp + (size_t)31*655360;          // 13.9 MB
  unsigned short* fbT = (unsigned short*)Bf;
  float* gpart = (float*)Zn;           // gb partials (time-disjoint with Zn)
  float* bpart = gpart + 1048576;

  k_wprep<<<dim3(31, 32), dim3(256), 0, stream>>>(conv_w, tl_c1_w, wp);
  k_gb_part<<<dim3(32, 8), dim3(256), 0, stream>>>(spk, noise, g_w, b_w,
      tl_g_w, tl_b_w, gpart, bpart);
  k_gb_red<<<dim3(512), dim3(256), 0, stream>>>(gpart, bpart, g_b, b_b,
      tl_g_b, tl_b_b, gammas, betas);
  k_embed2<<<dim3(80), dim3(256), 0, stream>>>(inputs, emb, x, statp);

  const int dils[3] = {1, 2, 4};
  for (int blk = 0; blk < 10; ++blk) {
    const float* srcs[3] = {x, A, Bf};
    float*       dsts[3] = {A, Bf, x};   // ping-pong; never in-place (R2 race)
    for (int j = 0; j < 3; ++j) {
      int idx = blk*3 + j;
      int mode = (j == 2) ? 1 : 0;
      k_norm<<<dim3(16, 8, 10), dim3(256), 0, stream>>>(srcs[j],
          statp, gammas + idx*4096, betas + idx*4096, Zn);
      k_convm<5><<<dim3(80, 8), dim3(256), 0, stream>>>(Zn, dsts[j],
          statp, wp + (size_t)idx*655360, conv_b + idx*256, dils[j], mode);
    }
  }
  // token-length head
  k_norm<<<dim3(16, 8, 10), dim3(256), 0, stream>>>(x,
      statp, gammas + 30*4096, betas + 30*4096, Zn);
  k_convm<1><<<dim3(80, 8), dim3(256), 0, stream>>>(Zn, A,
      statp, wp + (size_t)30*655360, tl_c1_b, 1, 0);
  k_statred<<<dim3(2), dim3(256), 0, stream>>>(statp, stat31);
  k_tl2<<<dim3(2400), dim3(256), 0, stream>>>(A, stat31,
      gammas + 31*4096, betas + 31*4096, tl_c2_w, tl_c2_b, tl);
  k_cumsum<<<dim3(16), dim3(64), 0, stream>>>(tl, cen, out + 24576000);
  // alignment einsum (bf16 MFMA)
  k_tobf16<<<dim3(16, 10, 4), dim3(256), 0, stream>>>(x, fbT);
  k_align2<<<dim3(16, 94), dim3(256), 0, stream>>>(fbT, cen, out);
}

// Round 12
// 1503.542 us; speedup vs baseline: 2.1866x; 1.0277x over previous
//
#include <hip/hip_runtime.h>
#include <math.h>
#include <stdint.h>

#define EPSv 1e-5f

typedef short short8 __attribute__((ext_vector_type(8)));
typedef float floatx4 __attribute__((ext_vector_type(4)));

__device__ __forceinline__ unsigned short f2bf(float x) {
  unsigned u = __float_as_uint(x);
  unsigned r = (u + 0x7fffu + ((u >> 16) & 1u)) >> 16;
  return (unsigned short)r;
}

// global->LDS direct DMA, 16B/lane (explicit address spaces; CK cast pattern).
__device__ __forceinline__ void gld_lds16(const void* g, void* l) {
  __builtin_amdgcn_global_load_lds(
      (const __attribute__((address_space(1))) unsigned*)(uintptr_t)g,
      (__attribute__((address_space(3))) unsigned*)(uintptr_t)l,
      16, 0, 0);
}

// ---------------- gamma/beta via k-slice partials ----------------
__global__ __launch_bounds__(256) void k_gb_part(const float* __restrict__ spk,
                             const float* __restrict__ noise,
                             const float* __restrict__ g_w, const float* __restrict__ b_w,
                             const float* __restrict__ tl_g_w, const float* __restrict__ tl_b_w,
                             float* __restrict__ gpart, float* __restrict__ bpart) {
  __shared__ float condl[16][32];
  int i = blockIdx.x, ks = blockIdx.y;
  int t = threadIdx.x;
  for (int idx = t; idx < 512; idx += 256) {
    int b = idx >> 5, kk = idx & 31;
    int k = ks*32 + kk;
    condl[b][kk] = (k < 128) ? spk[b*128 + k] : noise[b*128 + k - 128];
  }
  __syncthreads();
  const float *gw, *bw;
  if (i < 30) { gw = g_w + (size_t)i*65536; bw = b_w + (size_t)i*65536; }
  else        { gw = tl_g_w + (size_t)(i-30)*65536; bw = tl_b_w + (size_t)(i-30)*65536; }
  int co = t;
  float g[16], bt[16];
  #pragma unroll
  for (int b = 0; b < 16; ++b) { g[b] = 0.f; bt[b] = 0.f; }
  for (int kk = 0; kk < 32; ++kk) {
    float gwv = gw[(size_t)(ks*32 + kk)*256 + co];
    float bwv = bw[(size_t)(ks*32 + kk)*256 + co];
    #pragma unroll
    for (int b = 0; b < 16; ++b) {
      float cv = condl[b][kk];
      g[b]  = fmaf(cv, gwv, g[b]);
      bt[b] = fmaf(cv, bwv, bt[b]);
    }
  }
  size_t base = ((size_t)(i*8 + ks)*16)*256 + co;
  #pragma unroll
  for (int b = 0; b < 16; ++b) {
    gpart[base + (size_t)b*256] = g[b];
    bpart[base + (size_t)b*256] = bt[b];
  }
}

__global__ void k_gb_red(const float* __restrict__ gpart, const float* __restrict__ bpart,
                         const float* __restrict__ g_b, const float* __restrict__ b_b,
                         const float* __restrict__ tl_g_b, const float* __restrict__ tl_b_b,
                         float* __restrict__ gammas, float* __restrict__ betas) {
  int idx = blockIdx.x*256 + threadIdx.x;    // 0..131071
  int i = idx >> 12, rem = idx & 4095;
  int co = rem & 255;
  float gs = 0.f, bs = 0.f;
  #pragma unroll
  for (int ks = 0; ks < 8; ++ks) {
    size_t p = ((size_t)(i*8 + ks) << 12) + rem;
    gs += gpart[p];
    bs += bpart[p];
  }
  float gbias = (i < 30) ? g_b[i*256 + co] : tl_g_b[(i-30)*256 + co];
  float bbias = (i < 30) ? b_b[i*256 + co] : tl_b_b[(i-30)*256 + co];
  gammas[idx] = 1.0f + gs + gbias;
  betas [idx] = bs + bbias;
}

// ---------------- weight prepack ----------------
template<int TAPS>
__device__ __forceinline__ void wprep_body(const float* __restrict__ src,
                                           unsigned short* __restrict__ dst,
                                           int cotile, int chunk, int t) {
  int cow = t >> 2, ci8 = (t & 3) * 8;
  const float* s0 = src + ((size_t)(cotile*64 + cow)*256 + chunk*32 + ci8)*TAPS;
  float v[8*TAPS];
  #pragma unroll
  for (int i = 0; i < 8*TAPS; ++i) v[i] = s0[i];
  unsigned short* dblk = dst + (size_t)cotile*(8*TAPS*4096) + (size_t)chunk*(TAPS*4096);
  #pragma unroll
  for (int tap = 0; tap < TAPS; ++tap) {
    unsigned hi2[4], lo2[4];
    #pragma unroll
    for (int jj = 0; jj < 4; ++jj) {
      float a = v[(jj*2+0)*TAPS + tap], b = v[(jj*2+1)*TAPS + tap];
      unsigned short ha = f2bf(a), hb = f2bf(b);
      unsigned short la = f2bf(a - __uint_as_float((unsigned)ha << 16));
      unsigned short lb = f2bf(b - __uint_as_float((unsigned)hb << 16));
      hi2[jj] = (unsigned)ha | ((unsigned)hb << 16);
      lo2[jj] = (unsigned)la | ((unsigned)lb << 16);
    }
    uint4 H; H.x = hi2[0]; H.y = hi2[1]; H.z = hi2[2]; H.w = hi2[3];
    uint4 L; L.x = lo2[0]; L.y = lo2[1]; L.z = lo2[2]; L.w = lo2[3];
    *(uint4*)(dblk + (size_t)(tap*2)*2048 + cow*32 + ci8) = H;
    *(uint4*)(dblk + (size_t)(tap*2+1)*2048 + cow*32 + ci8) = L;
  }
}

__global__ __launch_bounds__(256) void k_wprep(const float* __restrict__ conv_w,
                                               const float* __restrict__ tl_c1_w,
                                               unsigned short* __restrict__ wp) {
  int cc = blockIdx.x;
  int cotile = blockIdx.y >> 3, chunk = blockIdx.y & 7;
  if (cc == 30) wprep_body<1>(tl_c1_w, wp + (size_t)30*655360, cotile, chunk, threadIdx.x);
  else          wprep_body<5>(conv_w + (size_t)cc*327680, wp + (size_t)cc*655360, cotile, chunk, threadIdx.x);
}

// ---------------- embedding gather + 80 per-block stats partials ----------------
__global__ void k_embed2(const int* __restrict__ inp, const float* __restrict__ emb,
                         float* __restrict__ x, float* __restrict__ statp) {
  int bx = blockIdx.x;            // 80 blocks x 120 rows
  int c = threadIdx.x;
  int r0 = bx * 120;
  float s = 0.f, s2 = 0.f;
  for (int r = 0; r < 120; ++r) {
    int row = inp[r0 + r];
    float v = emb[(size_t)row*256 + c];
    x[(size_t)(r0 + r)*256 + c] = v;
    s += v; s2 = fmaf(v, v, s2);
  }
  statp[(size_t)bx*512 + c] = s;
  statp[(size_t)bx*512 + 256 + c] = s2;
}

// ---------------- normalize + ReLU + bf16 hi/lo split (inline 80-partial reduce) ----------------
__global__ __launch_bounds__(256) void k_norm(const float* __restrict__ z,
                      const float* __restrict__ statp,
                      const float* __restrict__ gam, const float* __restrict__ bet,
                      unsigned short* __restrict__ zn) {
  __shared__ float s_sc[32];
  __shared__ float s_sh[32];
  __shared__ float red[2][32][8];
  int b = blockIdx.x, chunk = blockIdx.y, sub = blockIdx.z;
  int t = threadIdx.x;
  {
    int ch = t >> 3, g = t & 7;
    int c = chunk*32 + ch;
    float s = 0.f, s2 = 0.f;
    for (int p = g; p < 80; p += 8) {
      s  += statp[(size_t)p*512 + c];
      s2 += statp[(size_t)p*512 + 256 + c];
    }
    red[0][ch][g] = s; red[1][ch][g] = s2;
  }
  __syncthreads();
  if (t < 32) {
    float s = 0.f, s2 = 0.f;
    #pragma unroll
    for (int g = 0; g < 8; ++g) { s += red[0][t][g]; s2 += red[1][t][g]; }
    int c = chunk*32 + t;
    float mu = s * (1.0f/9600.0f);
    float var = s2 * (1.0f/9600.0f) - mu*mu;
    float rs = rsqrtf(var + EPSv);
    float scale = rs * gam[b*256 + c];
    s_sc[t] = scale;
    s_sh[t] = fmaf(-mu, scale, bet[b*256 + c]);
  }
  __syncthreads();
  int srow = t >> 3, fq = t & 7;
  float4 sc4 = *(const float4*)&s_sc[fq*4];
  float4 sh4 = *(const float4*)&s_sh[fq*4];
  unsigned short* zh = zn + ((size_t)b*8 + chunk)*54400 + fq*4;
  unsigned short* zl = zh + 27200;
  const float* zb = z + (size_t)b*600*256 + chunk*32 + fq*4;
  int r0 = sub*68;
  #pragma unroll
  for (int i = 0; i < 3; ++i) {
    int rr = i*32 + srow;
    if (rr < 68) {
      int r = r0 + rr;
      int l = r - 8;
      uint2 vh; vh.x = 0u; vh.y = 0u;
      uint2 vl; vl.x = 0u; vl.y = 0u;
      if (l >= 0 && l < 600) {
        float4 zv = *(const float4*)&zb[(size_t)l*256];
        float v0 = fmaxf(fmaf(zv.x, sc4.x, sh4.x), 0.f);
        float v1 = fmaxf(fmaf(zv.y, sc4.y, sh4.y), 0.f);
        float v2 = fmaxf(fmaf(zv.z, sc4.z, sh4.z), 0.f);
        float v3 = fmaxf(fmaf(zv.w, sc4.w, sh4.w), 0.f);
        unsigned short h0 = f2bf(v0), h1 = f2bf(v1), h2 = f2bf(v2), h3 = f2bf(v3);
        unsigned short e0 = f2bf(v0 - __uint_as_float((unsigned)h0 << 16));
        unsigned short e1 = f2bf(v1 - __uint_as_float((unsigned)h1 << 16));
        unsigned short e2 = f2bf(v2 - __uint_as_float((unsigned)h2 << 16));
        unsigned short e3 = f2bf(v3 - __uint_as_float((unsigned)h3 << 16));
        vh.x = (unsigned)h0 | ((unsigned)h1 << 16);
        vh.y = (unsigned)h2 | ((unsigned)h3 << 16);
        vl.x = (unsigned)e0 | ((unsigned)e1 << 16);
        vl.y = (unsigned)e2 | ((unsigned)e3 << 16);
      }
      *(uint2*)&zh[(size_t)r*40] = vh;
      *(uint2*)&zl[(size_t)r*40] = vl;
    }
  }
}

// ---------------- MFMA dilated conv (R8 structure: stage-ahead dbuf — control) ----------------
template<int TAPS>
__global__ __launch_bounds__(256, 3) void k_convm(const unsigned short* __restrict__ zn,
                        float* __restrict__ out, float* __restrict__ statp,
                        const unsigned short* __restrict__ wpc,
                        const float* __restrict__ bias, int dil, int mode) {
  __shared__ __align__(16) unsigned short Zhi[2][6144];   // 12 x 1024B DMA each
  __shared__ __align__(16) unsigned short Zlo[2][6144];
  __shared__ float lsum[32];
  __shared__ float lsq[32];
  int t = threadIdx.x;
  int bx = blockIdx.x;          // 16 b x 5 l-tiles
  int b  = bx / 5;
  int l0 = (bx % 5) * 128;
  int y = blockIdx.y;
  int co0 = y * 32;
  int cobase = (y & 1) * 32;
  int PAD = ((TAPS - 1)/2) * dil;
  int w = t >> 6, lane = t & 63;
  int lsub = (w & 1) * 64, cosub = (w >> 1) * 16;
  int quad = lane >> 4, nlan = lane & 15;
  if (t < 32) { lsum[t] = 0.f; lsq[t] = 0.f; }

  floatx4 acc[4];
  #pragma unroll
  for (int mt = 0; mt < 4; ++mt) acc[mt] = (floatx4){0.f,0.f,0.f,0.f};

  const unsigned short* zbase = zn + (size_t)b*435200 + (size_t)(l0 - PAD + 8)*40 + (size_t)lane*8;
  int ar[4];
  #pragma unroll
  for (int mt = 0; mt < 4; ++mt) ar[mt] = (lsub + mt*16 + nlan) * 40 + quad * 8;

  #define STAGEZ(ch, bf) do {                                             \
    const unsigned short* srcp = zbase + (size_t)(ch)*54400;              \
    for (int i = w; i < 24; i += 4) {                                     \
      int p = (i >= 12) ? 1 : 0;                                          \
      int k = i - p*12;                                                   \
      gld_lds16(srcp + p*27200 + k*512, (p ? Zlo[bf] : Zhi[bf]) + k*512); \
    }                                                                     \
  } while (0)

  STAGEZ(0, 0);
  __syncthreads();

  for (int chunk = 0; chunk < 8; ++chunk) {
    int cb = chunk & 1;
    if (chunk < 7) STAGEZ(chunk + 1, cb ^ 1);   // issue early: hides under compute
    const unsigned short* pch = wpc + (size_t)((y >> 1)*8 + chunk) * (TAPS*4096);
    short8 bh[TAPS], bl[TAPS];
    int cw = (cobase + cosub + nlan)*32 + quad*8;
    #pragma unroll
    for (int tap = 0; tap < TAPS; ++tap) {
      bh[tap] = *(const short8*)(pch + (size_t)(tap*2)*2048 + cw);
      bl[tap] = *(const short8*)(pch + (size_t)(tap*2+1)*2048 + cw);
    }
    #pragma unroll
    for (int tap = 0; tap < TAPS; ++tap) {
      int sh = tap * dil * 40;
      #pragma unroll
      for (int mt = 0; mt < 4; ++mt) {
        short8 ah = *(const short8*)&Zhi[cb][ar[mt] + sh];
        short8 al = *(const short8*)&Zlo[cb][ar[mt] + sh];
        acc[mt] = __builtin_amdgcn_mfma_f32_16x16x32_bf16(ah, bh[tap], acc[mt], 0, 0, 0);
        acc[mt] = __builtin_amdgcn_mfma_f32_16x16x32_bf16(ah, bl[tap], acc[mt], 0, 0, 0);
        acc[mt] = __builtin_amdgcn_mfma_f32_16x16x32_bf16(al, bh[tap], acc[mt], 0, 0, 0);
      }
    }
    __syncthreads();   // drains chunk+1 DMA + this chunk's ds_reads
  }
  #undef STAGEZ

  float bsv = bias[co0 + cosub + nlan];
  float ssum = 0.f, ssq = 0.f;
  #pragma unroll
  for (int mt = 0; mt < 4; ++mt) {
    #pragma unroll
    for (int r = 0; r < 4; ++r) {
      int l = l0 + lsub + mt*16 + quad*4 + r;
      if (l < 600) {
        float v = acc[mt][r] + bsv;
        float* dst = &out[((size_t)(b*600 + l))*256 + co0 + cosub + nlan];
        if (mode) v += *dst;
        *dst = v;
        ssum += v;
        ssq = fmaf(v, v, ssq);
      }
    }
  }
  ssum += __shfl_xor(ssum, 16, 64);
  ssum += __shfl_xor(ssum, 32, 64);
  ssq  += __shfl_xor(ssq, 16, 64);
  ssq  += __shfl_xor(ssq, 32, 64);
  if (quad == 0) {
    atomicAdd(&lsum[cosub + nlan], ssum);   // LDS-scope only
    atomicAdd(&lsq [cosub + nlan], ssq);
  }
  __syncthreads();
  if (t < 32) {
    statp[(size_t)bx*512 + co0 + t] = lsum[t];
    statp[(size_t)bx*512 + 256 + co0 + t] = lsq[t];
  }
}

// ---------------- reduce stats partials -> dense 512 raw sums (for k_tl2) ----------------
__global__ void k_statred(const float* __restrict__ sp, float* __restrict__ dst) {
  int idx = blockIdx.x*256 + threadIdx.x;
  float s = 0.f;
  for (int p = 0; p < 80; ++p) s += sp[(size_t)p*512 + idx];
  dst[idx] = s;
}

// ---------------- token-length final 256->1 conv + relu ----------------
__global__ void k_tl2(const float* __restrict__ z, const float* __restrict__ stat,
                      const float* __restrict__ gam, const float* __restrict__ bet,
                      const float* __restrict__ w2, const float* __restrict__ b2,
                      float* __restrict__ tl) {
  int t = threadIdx.x;
  int row = blockIdx.x * 4 + (t >> 6);
  int lane = t & 63;
  int b = row / 600;
  float4 s1 = *(const float4*)&stat[lane*4];
  float4 s2 = *(const float4*)&stat[256 + lane*4];
  float4 gm = *(const float4*)&gam[b*256 + lane*4];
  float4 bt = *(const float4*)&bet[b*256 + lane*4];
  float sc[4], sh[4];
  {
    float sv[4] = {s1.x, s1.y, s1.z, s1.w};
    float qv[4] = {s2.x, s2.y, s2.z, s2.w};
    float gv[4] = {gm.x, gm.y, gm.z, gm.w};
    float bv[4] = {bt.x, bt.y, bt.z, bt.w};
    #pragma unroll
    for (int i = 0; i < 4; ++i) {
      float mu = sv[i] * (1.0f/9600.0f);
      float var = qv[i] * (1.0f/9600.0f) - mu*mu;
      float rs = rsqrtf(var + EPSv);
      sc[i] = rs * gv[i];
      sh[i] = fmaf(-mu, sc[i], bv[i]);
    }
  }
  float4 zr = *(const float4*)&z[(size_t)row*256 + lane*4];
  float4 wr = *(const float4*)&w2[lane*4];
  float z0 = fmaxf(fmaf(zr.x, sc[0], sh[0]), 0.f);
  float z1 = fmaxf(fmaf(zr.y, sc[1], sh[1]), 0.f);
  float z2 = fmaxf(fmaf(zr.z, sc[2], sh[2]), 0.f);
  float z3 = fmaxf(fmaf(zr.w, sc[3], sh[3]), 0.f);
  float s = z0*wr.x + z1*wr.y + z2*wr.z + z3*wr.w;
  for (int m = 32; m >= 1; m >>= 1) s += __shfl_xor(s, m, 64);
  if (lane == 0) tl[row] = fmaxf(s + b2[0], 0.f);
}

// ---------------- per-batch cumsum -> ends (output 1) + centers ----------------
__global__ void k_cumsum(const float* __restrict__ tl, float* __restrict__ centers,
                         float* __restrict__ out_len) {
  int b = blockIdx.x; int lane = threadIdx.x;
  float carry = 0.f;
  for (int ch = 0; ch < 10; ++ch) {
    int l = ch*64 + lane;
    float v = (l < 600) ? tl[b*600 + l] : 0.f;
    float s = v;
    #pragma unroll
    for (int off = 1; off < 64; off <<= 1) {
      float n = __shfl_up(s, off, 64);
      if (lane >= off) s += n;
    }
    float ends = carry + s;
    if (l < 600) {
      centers[b*600 + l] = ends - 0.5f*v;
      out_len[b*600 + l] = ends;
    }
    carry = __shfl(ends, 63, 64);
  }
}

// ---------------- fp32 (b,l,c) -> bf16 (b,c,l) transpose, l padded to 640 ----------------
__global__ void k_tobf16(const float* __restrict__ x, unsigned short* __restrict__ fbT) {
  __shared__ unsigned short T[64*66];
  int b = blockIdx.x, lt = blockIdx.y, ct = blockIdx.z;
  int t = threadIdx.x;
  int i4 = t >> 6;
  int j = t & 63;
  #pragma unroll
  for (int r = 0; r < 16; ++r) {
    int li = i4*16 + r;
    int l = lt*64 + li;
    float v = (l < 600) ? x[((size_t)(b*600 + l))*256 + ct*64 + j] : 0.f;
    T[j*66 + li] = f2bf(v);
  }
  __syncthreads();
  int row = t >> 2, seg = (t & 3) * 16;
  unsigned vv[8];
  #pragma unroll
  for (int k = 0; k < 8; ++k)
    vv[k] = *(const unsigned*)&T[row*66 + seg + k*2];
  size_t dsth = ((size_t)(b*256 + ct*64 + row))*640 + lt*64 + seg;
  unsigned* du = (unsigned*)fbT;
  uint4 a; a.x = vv[0]; a.y = vv[1]; a.z = vv[2]; a.w = vv[3];
  uint4 c4; c4.x = vv[4]; c4.y = vv[5]; c4.z = vv[6]; c4.w = vv[7];
  *(uint4*)(du + dsth/2) = a;
  *(uint4*)(du + dsth/2 + 4) = c4;
}

// ---------------- alignment einsum (R12: cheap interval-bound mo + direct writes) ----------------
// R11 post-mortem: LDS-slab epilogue cost +12us (writes were already block-coalesced:
// the 4 waves jointly cover c 0..255 per o-row) -> reverted to direct stores.
// Phase-1 exact row-max scan (~800 VALU/lane) replaced by interval bound: cen is
// monotone, so mo = -minDo^2/10 >= true max (slack <= (jump/2)^2/10, negligible);
// softmax invariant for any mo >= max (exponents <= 0), skip threshold only safer.
__global__ __launch_bounds__(256, 4) void k_align2(const unsigned short* __restrict__ fbT,
                        const float* __restrict__ centers, float* __restrict__ outp) {
  __shared__ float cen[600];
  __shared__ float mrow[64];
  __shared__ float isum[64];
  __shared__ unsigned actm_s;
  __shared__ unsigned short Wt[2][64*80];
  int b = blockIdx.x;
  int o0 = blockIdx.y * 64;
  int t = threadIdx.x;
  int wv = t >> 6, lane = t & 63;
  for (int i = t; i < 600; i += 256) cen[i] = centers[b*600 + i];
  __syncthreads();

  // wave 0: per-o interval-bound max + active-chunk mask in one cheap pass
  if (wv == 0) {
    float opos_l = (float)(o0 + lane);
    float dmin = 3.0e38f;
    float Dos[10];
    #pragma unroll
    for (int ch = 0; ch < 10; ++ch) {
      float clo = cen[ch*64];
      float chi = cen[(ch*64 + 63 < 599) ? ch*64 + 63 : 599];
      float Do = fmaxf(fmaxf(clo - opos_l, opos_l - chi), 0.f);
      Dos[ch] = Do;
      dmin = fminf(dmin, Do);
    }
    float mo_l = -dmin*dmin*0.1f;     // >= true row max
    mrow[lane] = mo_l;
    unsigned am = 0;
    #pragma unroll
    for (int ch = 0; ch < 10; ++ch) {
      bool near = (fmaf(-Dos[ch]*Dos[ch], 0.1f, -mo_l) >= -80.f);
      if (__ballot(near) != 0ull) am |= (1u << ch);
    }
    if (lane == 0) actm_s = am;
  }
  __syncthreads();

  floatx4 acc[4][4];
  #pragma unroll
  for (int i = 0; i < 4; ++i)
    #pragma unroll
    for (int j = 0; j < 4; ++j)
      acc[i][j] = (floatx4){0.f, 0.f, 0.f, 0.f};
  int quad = lane >> 4;
  int nlan = lane & 15;
  int oi_w = t >> 2;
  int sbase = t & 3;
  float mo = mrow[oi_w];
  float opos_w = (float)(o0 + oi_w);
  float psum = 0.f;
  const unsigned short* srcb = fbT + ((size_t)b*256)*640;
  const unsigned short* fbl = srcb + (size_t)(wv*64 + nlan)*640 + quad*8;
  unsigned actm = actm_s;

  #define STAGE_WT(CH, BF) do {                                              \
    int lcs = (CH) * 64;                                                     \
    _Pragma("unroll")                                                        \
    for (int sidx = 0; sidx < 2; ++sidx) {                                   \
      int seg = sbase + sidx*4;                                              \
      unsigned pk[4];                                                        \
      _Pragma("unroll")                                                      \
      for (int jj = 0; jj < 8; jj += 2) {                                    \
        int li = lcs + seg*8 + jj;                                           \
        float e0 = 0.f, e1 = 0.f;                                            \
        if (li < 600)     { float d = cen[li] - opos_w;     e0 = __expf(fmaf(-d*d, 0.1f, -mo)); } \
        if (li + 1 < 600) { float d = cen[li + 1] - opos_w; e1 = __expf(fmaf(-d*d, 0.1f, -mo)); } \
        psum += e0 + e1;                                                     \
        pk[jj>>1] = (unsigned)f2bf(e0) | ((unsigned)f2bf(e1) << 16);         \
      }                                                                      \
      uint4 v; v.x = pk[0]; v.y = pk[1]; v.z = pk[2]; v.w = pk[3];           \
      *(uint4*)&Wt[BF][oi_w*80 + seg*8] = v;                                 \
    }                                                                        \
  } while (0)

  int ch = __ffs(actm) - 1;     // actm != 0 guaranteed (nearest chunk active)
  int buf = 0;
  STAGE_WT(ch, 0);
  __syncthreads();

  while (ch >= 0) {
    unsigned rem = actm & ~((2u << ch) - 1u);   // bits strictly above ch
    int nxt = rem ? (__ffs(rem) - 1) : -1;
    int lc0 = ch * 64;
    short8 bfr[2][4];
    #pragma unroll
    for (int ks = 0; ks < 2; ++ks)
      #pragma unroll
      for (int nt = 0; nt < 4; ++nt)
        bfr[ks][nt] = *(const short8*)(fbl + (size_t)nt*16*640 + lc0 + ks*32);
    if (nxt >= 0) STAGE_WT(nxt, buf ^ 1);
    #pragma unroll
    for (int ks = 0; ks < 2; ++ks) {
      int ko = ks*32 + quad*8;
      short8 af[4];
      #pragma unroll
      for (int mt = 0; mt < 4; ++mt)
        af[mt] = *(const short8*)&Wt[buf][(mt*16 + nlan)*80 + ko];
      #pragma unroll
      for (int mt = 0; mt < 4; ++mt)
        #pragma unroll
        for (int nt = 0; nt < 4; ++nt)
          acc[mt][nt] = __builtin_amdgcn_mfma_f32_16x16x32_bf16(af[mt], bfr[ks][nt], acc[mt][nt], 0, 0, 0);
    }
    __syncthreads();   // stage(nxt) visible; reads of buf done before re-stage
    ch = nxt; buf ^= 1;
  }
  #undef STAGE_WT

  psum += __shfl_xor(psum, 1, 64);
  psum += __shfl_xor(psum, 2, 64);
  if ((t & 3) == 0) isum[oi_w] = 1.0f / psum;
  __syncthreads();

  // direct epilogue (R8): per o-row the 4 waves jointly write c 0..255 -> coalesced at L2
  #pragma unroll
  for (int mt = 0; mt < 4; ++mt) {
    #pragma unroll
    for (int r = 0; r < 4; ++r) {
      int oi = mt*16 + quad*4 + r;
      int o = o0 + oi;
      if (o < 6000) {
        float sc = isum[oi];
        #pragma unroll
        for (int nt = 0; nt < 4; ++nt) {
          int c = wv*64 + nt*16 + nlan;
          outp[((size_t)b*6000 + o)*256 + c] = acc[mt][nt][r] * sc;
        }
      }
    }
  }
}

extern "C" void kernel_launch(void* const* d_in, const int* in_sizes, int n_in,
                              void* d_out, int out_size, void* d_ws, size_t ws_size,
                              hipStream_t stream) {
  const int*   inputs = (const int*)  d_in[0];
  const float* spk    = (const float*)d_in[1];
  const float* noise  = (const float*)d_in[2];
  const float* emb    = (const float*)d_in[3];
  const float* conv_w = (const float*)d_in[4];
  const float* conv_b = (const float*)d_in[5];
  const float* g_w    = (const float*)d_in[6];
  const float* g_b    = (const float*)d_in[7];
  const float* b_w    = (const float*)d_in[8];
  const float* b_b    = (const float*)d_in[9];
  const float* tl_g_w = (const float*)d_in[10];
  const float* tl_g_b = (const float*)d_in[11];
  const float* tl_b_w = (const float*)d_in[12];
  const float* tl_b_b = (const float*)d_in[13];
  const float* tl_c1_w = (const float*)d_in[14];
  const float* tl_c1_b = (const float*)d_in[15];
  const float* tl_c2_w = (const float*)d_in[16];
  const float* tl_c2_b = (const float*)d_in[17];
  float* out = (float*)d_out;

  float* ws = (float*)d_ws;
  float* x       = ws;                 // 2457600
  float* A       = x + 2457600;        // 2457600
  float* Bf      = A + 2457600;        // 2457600 (reused as fbT at the end)
  float* gammas  = Bf + 2457600;       // 131072
  float* betas   = gammas + 131072;    // 131072
  float* statp   = betas + 131072;     // 80 x 512 partials (region reserves 81920)
  float* stat31  = statp + 81920;      // dense 512
  float* tl      = stat31 + 512;       // 9600
  float* cen     = tl + 9600;          // 9600
  unsigned short* wp = (unsigned short*)(cen + 9600);   // ~40.6 MB
  unsigned short* Zn = wp + (size_t)31*655360;          // 13.9 MB
  unsigned short* fbT = (unsigned short*)Bf;
  float* gpart = (float*)Zn;           // gb partials (time-disjoint with Zn)
  float* bpart = gpart + 1048576;

  k_wprep<<<dim3(31, 32), dim3(256), 0, stream>>>(conv_w, tl_c1_w, wp);
  k_gb_part<<<dim3(32, 8), dim3(256), 0, stream>>>(spk, noise, g_w, b_w,
      tl_g_w, tl_b_w, gpart, bpart);
  k_gb_red<<<dim3(512), dim3(256), 0, stream>>>(gpart, bpart, g_b, b_b,
      tl_g_b, tl_b_b, gammas, betas);
  k_embed2<<<dim3(80), dim3(256), 0, stream>>>(inputs, emb, x, statp);

  const int dils[3] = {1, 2, 4};
  for (int blk = 0; blk < 10; ++blk) {
    const float* srcs[3] = {x, A, Bf};
    float*       dsts[3] = {A, Bf, x};   // ping-pong; never in-place (R2 race)
    for (int j = 0; j < 3; ++j) {
      int idx = blk*3 + j;
      int mode = (j == 2) ? 1 : 0;
      k_norm<<<dim3(16, 8, 10), dim3(256), 0, stream>>>(srcs[j],
          statp, gammas + idx*4096, betas + idx*4096, Zn);
      k_convm<5><<<dim3(80, 8), dim3(256), 0, stream>>>(Zn, dsts[j],
          statp, wp + (size_t)idx*655360, conv_b + idx*256, dils[j], mode);
    }
  }
  // token-length head
  k_norm<<<dim3(16, 8, 10), dim3(256), 0, stream>>>(x,
      statp, gammas + 30*4096, betas + 30*4096, Zn);
  k_convm<1><<<dim3(80, 8), dim3(256), 0, stream>>>(Zn, A,
      statp, wp + (size_t)30*655360, tl_c1_b, 1, 0);
  k_statred<<<dim3(2), dim3(256), 0, stream>>>(statp, stat31);
  k_tl2<<<dim3(2400), dim3(256), 0, stream>>>(A, stat31,
      gammas + 31*4096, betas + 31*4096, tl_c2_w, tl_c2_b, tl);
  k_cumsum<<<dim3(16), dim3(64), 0, stream>>>(tl, cen, out + 24576000);
  // alignment einsum (bf16 MFMA)
  k_tobf16<<<dim3(16, 10, 4), dim3(256), 0, stream>>>(x, fbT);
  k_align2<<<dim3(16, 94), dim3(256), 0, stream>>>(fbT, cen, out);
}